// Round 12
// baseline (266.038 us; speedup 1.0000x reference)
//
#include <hip/hip_runtime.h>
#include <hip/hip_bf16.h>

#define TK 20
#define BN 65536

typedef const float* fpc;
typedef __attribute__((ext_vector_type(8))) short short8;
typedef __attribute__((ext_vector_type(4))) float floatx4;

// f32 -> bf16 bits, round-to-nearest-even
__device__ __forceinline__ short f2b(float f){
  unsigned u = __float_as_uint(f);
  return (short)((u + 0x7fffu + ((u >> 16) & 1u)) >> 16);
}
__device__ __forceinline__ float b2fu(unsigned short u){
  return __uint_as_float(((unsigned)u) << 16);
}

// ---------------- K1: fused graph (blocks 0..255) + xl MFMA GEMM (blocks 256..1279) ----------------
__global__ void __launch_bounds__(256) k_gx(fpc data, fpc emb, fpc lin_w, fpc att_i, fpc att_j,
        fpc att_em_i, fpc att_em_j,
        int* __restrict__ topk, float* __restrict__ emi, float* __restrict__ emj,
        __hip_bfloat16* __restrict__ xl, float* __restrict__ aip, float* __restrict__ ajp){
  __shared__ float s_cos[256];
  __shared__ float s_wi[64];
  const int t = threadIdx.x, w = t >> 6, lane = t & 63;

  if (blockIdx.x < 256){
    // ----- graph part: top-20 cosine + emi/emj -----
    const int i = blockIdx.x;
    if (t < 64) s_wi[t] = emb[i*64 + t];
    __syncthreads();
    float dot = 0.f, nj = 0.f, ni = 0.f;
    for (int f = 0; f < 64; ++f){
      float wj = emb[t*64 + f], wi = s_wi[f];
      dot = fmaf(wi, wj, dot); nj = fmaf(wj, wj, nj); ni = fmaf(wi, wi, ni);
    }
    s_cos[t] = dot / (sqrtf(ni) * sqrtf(nj));
    __syncthreads();
    if (t < 64){
      float v0 = s_cos[t], v1 = s_cos[t+64], v2 = s_cos[t+128], v3 = s_cos[t+192];
      int taken = 0;
      for (int r = 0; r < TK; ++r){
        float bv = (taken & 1) ? -3.f : v0; int bi = t;
        float c;
        c = (taken & 2) ? -3.f : v1; if (c > bv){ bv = c; bi = t+64;  }
        c = (taken & 4) ? -3.f : v2; if (c > bv){ bv = c; bi = t+128; }
        c = (taken & 8) ? -3.f : v3; if (c > bv){ bv = c; bi = t+192; }
        for (int m = 1; m < 64; m <<= 1){
          float ov = __shfl_xor(bv, m, 64);
          int   oi = __shfl_xor(bi, m, 64);
          if (ov > bv || (ov == bv && oi < bi)){ bv = ov; bi = oi; }
        }
        if (t == 0) topk[i*TK + r] = bi;
        if ((bi & 63) == t) taken |= 1 << (bi >> 6);
      }
    } else if (t < 128){
      int d = t - 64;
      float wv = s_wi[d];
      float p1 = wv * att_em_i[d];
      float p2 = wv * att_em_j[d];
      for (int m = 1; m < 64; m <<= 1){
        p1 += __shfl_xor(p1, m, 64);
        p2 += __shfl_xor(p2, m, 64);
      }
      if (d == 0){ emi[i] = p1; emj[i] = p2; }
    }
    return;
  }

  // ----- xl part: data @ lin_w via MFMA 16x16x32 bf16 -----
  const int m = lane & 15, quad = lane >> 4;
  short8 B[4][2];
  #pragma unroll
  for (int ct = 0; ct < 4; ++ct)
    #pragma unroll
    for (int kc = 0; kc < 2; ++kc)
      #pragma unroll
      for (int j = 0; j < 8; ++j)
        B[ct][kc][j] = f2b(lin_w[(kc*32 + quad*8 + j)*64 + ct*16 + m]);

  const int rw = (blockIdx.x - 256)*64 + w*16;  // 1024 blocks x 64 rows
  short8 A0, A1;
  {
    const float4* ap0 = (const float4*)(data + (size_t)(rw + m)*64 + quad*8);
    float4 q0 = ap0[0], q1 = ap0[1];
    A0[0]=f2b(q0.x); A0[1]=f2b(q0.y); A0[2]=f2b(q0.z); A0[3]=f2b(q0.w);
    A0[4]=f2b(q1.x); A0[5]=f2b(q1.y); A0[6]=f2b(q1.z); A0[7]=f2b(q1.w);
    const float4* ap1 = (const float4*)(data + (size_t)(rw + m)*64 + 32 + quad*8);
    float4 q2 = ap1[0], q3 = ap1[1];
    A1[0]=f2b(q2.x); A1[1]=f2b(q2.y); A1[2]=f2b(q2.z); A1[3]=f2b(q2.w);
    A1[4]=f2b(q3.x); A1[5]=f2b(q3.y); A1[6]=f2b(q3.z); A1[7]=f2b(q3.w);
  }
  floatx4 acc[4];
  #pragma unroll
  for (int ct = 0; ct < 4; ++ct){
    floatx4 z = {0.f, 0.f, 0.f, 0.f};
    acc[ct] = __builtin_amdgcn_mfma_f32_16x16x32_bf16(A0, B[ct][0], z, 0, 0, 0);
    acc[ct] = __builtin_amdgcn_mfma_f32_16x16x32_bf16(A1, B[ct][1], acc[ct], 0, 0, 0);
  }
  float p1[4] = {0.f,0.f,0.f,0.f}, p2[4] = {0.f,0.f,0.f,0.f};
  #pragma unroll
  for (int ct = 0; ct < 4; ++ct){
    const float wi = att_i[ct*16 + m], wj = att_j[ct*16 + m];
    #pragma unroll
    for (int reg = 0; reg < 4; ++reg){
      float v = acc[ct][reg];
      const int row = rw + quad*4 + reg;
      xl[(size_t)row*64 + ct*16 + m] = __float2bfloat16(v);
      p1[reg] = fmaf(v, wi, p1[reg]);
      p2[reg] = fmaf(v, wj, p2[reg]);
    }
  }
  #pragma unroll
  for (int reg = 0; reg < 4; ++reg){
    #pragma unroll
    for (int s = 1; s < 16; s <<= 1){
      p1[reg] += __shfl_xor(p1[reg], s, 16);
      p2[reg] += __shfl_xor(p2[reg], s, 16);
    }
    if (m == 0){
      const int r = rw + quad*4 + reg;
      aip[r] = p1[reg];                      // emi/emj added in k_attn_agg
      ajp[r] = p2[reg];
    }
  }
}

// ---------------- K2: edge softmax + gather aggregation (bf16 agg out) + bn1 shadow stats ----------------
__global__ void __launch_bounds__(256) k_attn_agg(const int* __restrict__ topk,
                         const __hip_bfloat16* __restrict__ xl,
                         fpc aip, fpc ajp, fpc emi_g, fpc emj_g, fpc gnn_bias,
                         __hip_bfloat16* __restrict__ agg, float* __restrict__ bnsum){
  __shared__ float s_alpha[4][32];
  __shared__ int   s_src[4][32];
  __shared__ float s_ps[4][64], s_pq[4][64];
  const int t = threadIdx.x, w = t >> 6, lane = t & 63;
  const float bias = gnn_bias[lane];
  const int vbase = blockIdx.x*64 + w*16;    // 1024 blocks x 64 nodes; 16/wave
  float sum = 0.f, sq = 0.f;
  for (int j = 0; j < 16; ++j){
    const int v = vbase + j, i = v & 255, b = v >> 8;
    float lg = -1e30f; int sl = 0;
    if (lane < 21){
      sl = (lane < 20) ? topk[i*TK + lane] : i;
      if (lane == 20 || sl != i){            // remove_self_loops, keep appended loop
        float l = aip[v] + emi_g[i] + ajp[b*256 + sl] + emj_g[sl];
        lg = (l >= 0.f) ? l : 0.2f*l;        // leaky_relu(0.2)
      }
    }
    float m = lg;
    for (int s = 1; s < 32; s <<= 1) m = fmaxf(m, __shfl_xor(m, s, 32));
    float e = (lg > -1e29f) ? __expf(lg - m) : 0.f;
    float den = e;
    for (int s = 1; s < 32; s <<= 1) den += __shfl_xor(den, s, 32);
    if (lane < 21){ s_alpha[w][lane] = e / den; s_src[w][lane] = b*256 + sl; }
    float acc = bias;
    #pragma unroll
    for (int k = 0; k < 21; ++k)
      acc = fmaf(s_alpha[w][k], __bfloat162float(xl[(size_t)s_src[w][k]*64 + lane]), acc);
    agg[(size_t)v*64 + lane] = __float2bfloat16(acc);
    sum += acc; sq = fmaf(acc, acc, sq);
  }
  s_ps[w][lane] = sum; s_pq[w][lane] = sq;
  __syncthreads();
  if (t < 64){
    const int cp = (blockIdx.x & 7)*64;
    atomicAdd(&bnsum[cp + t],       s_ps[0][t] + s_ps[1][t] + s_ps[2][t] + s_ps[3][t]);
    atomicAdd(&bnsum[512 + cp + t], s_pq[0][t] + s_pq[1][t] + s_pq[2][t] + s_pq[3][t]);
  }
}

// ---------------- K3: fused encoder MFMA (bn1+relu at load) + bn2 stats; grid (128 kt, 4 bt) ----------------
// Each element of agg is read exactly once across the grid -> bn2 stats computed inline.
__global__ void __launch_bounds__(256) k_encstat(const __hip_bfloat16* __restrict__ agg, fpc enc_w,
                         fpc emb, fpc g1, fpc be1,
                         float* __restrict__ bnsum, float* __restrict__ part){
  const int t = threadIdx.x, w = t >> 6, lane = t & 63;
  const int m = lane & 15, quad = lane >> 4;
  const int kt = blockIdx.x, bt = blockIdx.y, kbase = kt*128;
  // bn1 constants for this lane's channels d = par*32 + quad*8 + j
  float sc_[2][8], sh_[2][8];
  #pragma unroll
  for (int par = 0; par < 2; ++par)
    #pragma unroll
    for (int j = 0; j < 8; ++j){
      const int d = par*32 + quad*8 + j;
      float S = 0.f, Q = 0.f;
      #pragma unroll
      for (int cp = 0; cp < 8; ++cp){ S += bnsum[cp*64 + d]; Q += bnsum[512 + cp*64 + d]; }
      float mean = S * (1.f/BN);
      float var  = Q * (1.f/BN) - mean*mean;
      sc_[par][j] = g1[d] * rsqrtf(var + 1e-5f);
      sh_[par][j] = be1[d] - mean*sc_[par][j];
    }
  // emb values: kc -> node kt*2+(kc>>1), channel (kc&1)*32+quad*8+j
  float e_[4][8];
  #pragma unroll
  for (int kc = 0; kc < 4; ++kc)
    #pragma unroll
    for (int j = 0; j < 8; ++j)
      e_[kc][j] = emb[(kt*2 + (kc >> 1))*64 + (kc & 1)*32 + quad*8 + j];

  float ys[2][8], yq[2][8];
  #pragma unroll
  for (int par = 0; par < 2; ++par)
    #pragma unroll
    for (int j = 0; j < 8; ++j){ ys[par][j] = 0.f; yq[par][j] = 0.f; }

  floatx4 acc[4];
  #pragma unroll
  for (int ct = 0; ct < 4; ++ct) acc[ct] = (floatx4){0.f, 0.f, 0.f, 0.f};

  const int row = bt*64 + w*16 + m;          // 4 bt x 4 w x 16 m = 256 rows
  #pragma unroll
  for (int kc = 0; kc < 4; ++kc){
    const int kof = kbase + kc*32 + quad*8;
    const int par = kc & 1;
    short8 Bf[4];
    #pragma unroll
    for (int ct = 0; ct < 4; ++ct)
      #pragma unroll
      for (int j = 0; j < 8; ++j)
        Bf[ct][j] = f2b(enc_w[(size_t)(kof + j)*64 + ct*16 + m]);
    // load 8 bf16 of agg, apply bn1+relu, collect y stats, build A frag
    uint4 uu = *(const uint4*)((const unsigned short*)agg + (size_t)row*16384 + kof);
    unsigned short h[8] = {
      (unsigned short)(uu.x & 0xffff), (unsigned short)(uu.x >> 16),
      (unsigned short)(uu.y & 0xffff), (unsigned short)(uu.y >> 16),
      (unsigned short)(uu.z & 0xffff), (unsigned short)(uu.z >> 16),
      (unsigned short)(uu.w & 0xffff), (unsigned short)(uu.w >> 16) };
    short8 Af;
    #pragma unroll
    for (int j = 0; j < 8; ++j){
      float x = b2fu(h[j]);
      float g = fmaxf(fmaf(x, sc_[par][j], sh_[par][j]), 0.f);
      Af[j] = f2b(g);
      float y = g * e_[kc][j];
      ys[par][j] += y;
      yq[par][j] = fmaf(y, y, yq[par][j]);
    }
    #pragma unroll
    for (int ct = 0; ct < 4; ++ct)
      acc[ct] = __builtin_amdgcn_mfma_f32_16x16x32_bf16(Af, Bf[ct], acc[ct], 0, 0, 0);
  }
  #pragma unroll
  for (int ct = 0; ct < 4; ++ct)
    #pragma unroll
    for (int reg = 0; reg < 4; ++reg){
      const int orow = bt*64 + w*16 + quad*4 + reg;
      part[(size_t)kt*16384 + orow*64 + ct*16 + m] = acc[ct][reg];
    }
  // bn2 stat reduce across the 16 m-lanes of each quad, then shadow atomics
  const int cp = ((kt*4 + bt) & 7)*64;
  #pragma unroll
  for (int par = 0; par < 2; ++par)
    #pragma unroll
    for (int j = 0; j < 8; ++j){
      float S = ys[par][j], Q = yq[par][j];
      #pragma unroll
      for (int s = 1; s < 16; s <<= 1){ S += __shfl_xor(S, s, 16); Q += __shfl_xor(Q, s, 16); }
      if (m == 0){
        const int d = par*32 + quad*8 + j;
        atomicAdd(&bnsum[1024 + cp + d], S);
        atomicAdd(&bnsum[1536 + cp + d], Q);
      }
    }
}

// ---------------- K4: reduce split-K partials + arrangement head (block = batch row) ----------------
__global__ void __launch_bounds__(256) k_redarr(const float* __restrict__ part,
                      fpc enc_b, fpc arr_w, fpc arr_b, float* __restrict__ out){
  __shared__ float s_enc[4][64];
  const int b = blockIdx.x, t = threadIdx.x, w = t >> 6, lane = t & 63;
  float s = 0.f;
  #pragma unroll 8
  for (int k = 0; k < 32; ++k)
    s += part[(size_t)(w*32 + k)*16384 + b*64 + lane];
  s_enc[w][lane] = s;
  __syncthreads();
  if (t < 64){
    float e = s_enc[0][t] + s_enc[1][t] + s_enc[2][t] + s_enc[3][t] + enc_b[t];
    float o[7];
    #pragma unroll
    for (int j = 0; j < 7; ++j) o[j] = e * arr_w[t*7 + j];
    #pragma unroll
    for (int j = 0; j < 7; ++j)
      #pragma unroll
      for (int m = 1; m < 64; m <<= 1) o[j] += __shfl_xor(o[j], m, 64);
    if (t == 0){
      #pragma unroll
      for (int j = 0; j < 7; ++j) out[65536 + b*7 + j] = o[j] + arr_b[j];
    }
  }
}

// ---------------- K5: score head -- bn1+bn2 on the fly from bf16 agg ----------------
__global__ void __launch_bounds__(256) k_score(const __hip_bfloat16* __restrict__ agg, fpc emb,
                      fpc g1, fpc be1, fpc g2, fpc be2,
                      const float* __restrict__ bnsum, fpc out_w, fpc out_b,
                      float* __restrict__ out){
  const int t = threadIdx.x, w = t >> 6, lane = t & 63;
  const int qc = lane & 15, rq = lane >> 4;
  float sc1[4], sh1[4], sc2[4], sh2[4], ow[4];
  #pragma unroll
  for (int k = 0; k < 4; ++k){
    const int d = qc*4 + k;
    float S1 = 0.f, Q1 = 0.f, S2 = 0.f, Q2 = 0.f;
    #pragma unroll
    for (int cp = 0; cp < 8; ++cp){
      S1 += bnsum[cp*64 + d];        Q1 += bnsum[512 + cp*64 + d];
      S2 += bnsum[1024 + cp*64 + d]; Q2 += bnsum[1536 + cp*64 + d];
    }
    float m1 = S1 * (1.f/BN), v1 = Q1 * (1.f/BN) - m1*m1;
    sc1[k] = g1[d] * rsqrtf(v1 + 1e-5f);
    sh1[k] = be1[d] - m1*sc1[k];
    float m2 = S2 * (1.f/BN), v2 = Q2 * (1.f/BN) - m2*m2;
    sc2[k] = g2[d] * rsqrtf(v2 + 1e-5f);
    sh2[k] = be2[d] - m2*sc2[k];
    ow[k]  = out_w[d];
  }
  const float ob = out_b[0];
  const float4* emb4 = (const float4*)emb;
  const int base = blockIdx.x*32 + w*8;      // 2048 blocks x 32 rows
  #pragma unroll
  for (int it = 0; it < 2; ++it){
    const int r = base + it*4 + rq;
    ushort4 u = *(const ushort4*)((const unsigned short*)agg + (size_t)r*64 + qc*4);
    float4 e4 = emb4[(r & 255)*16 + qc];
    float p = 0.f, g, y, yh;
    g = fmaxf(fmaf(b2fu(u.x), sc1[0], sh1[0]), 0.f); y = g*e4.x;
    yh = fmaxf(fmaf(y, sc2[0], sh2[0]), 0.f); p = fmaf(yh, ow[0], p);
    g = fmaxf(fmaf(b2fu(u.y), sc1[1], sh1[1]), 0.f); y = g*e4.y;
    yh = fmaxf(fmaf(y, sc2[1], sh2[1]), 0.f); p = fmaf(yh, ow[1], p);
    g = fmaxf(fmaf(b2fu(u.z), sc1[2], sh1[2]), 0.f); y = g*e4.z;
    yh = fmaxf(fmaf(y, sc2[2], sh2[2]), 0.f); p = fmaf(yh, ow[2], p);
    g = fmaxf(fmaf(b2fu(u.w), sc1[3], sh1[3]), 0.f); y = g*e4.w;
    yh = fmaxf(fmaf(y, sc2[3], sh2[3]), 0.f); p = fmaf(yh, ow[3], p);
    #pragma unroll
    for (int mm = 1; mm < 16; mm <<= 1) p += __shfl_xor(p, mm, 16);
    if (qc == 0) out[r] = p + ob;
  }
}

extern "C" void kernel_launch(void* const* d_in, const int* in_sizes, int n_in,
                              void* d_out, int out_size, void* d_ws, size_t ws_size,
                              hipStream_t stream) {
  fpc data     = (fpc)d_in[0];
  fpc emb      = (fpc)d_in[1];
  fpc lin_w    = (fpc)d_in[2];
  fpc att_i    = (fpc)d_in[3];
  fpc att_j    = (fpc)d_in[4];
  fpc att_em_i = (fpc)d_in[5];
  fpc att_em_j = (fpc)d_in[6];
  fpc gnn_bias = (fpc)d_in[7];
  fpc g1       = (fpc)d_in[8];
  fpc be1      = (fpc)d_in[9];
  fpc g2       = (fpc)d_in[10];
  fpc be2      = (fpc)d_in[11];
  fpc enc_w    = (fpc)d_in[12];
  fpc enc_b    = (fpc)d_in[13];
  fpc arr_w    = (fpc)d_in[14];
  fpc arr_b    = (fpc)d_in[15];
  fpc out_w    = (fpc)d_in[16];
  fpc out_b    = (fpc)d_in[17];

  float* fw = (float*)d_ws;
  int*   topk    = (int*)d_ws;            // [0, 5120)
  float* emi     = fw + 5120;             // 256
  float* emj     = fw + 5376;             // 256
  float* bnsum   = fw + 5632;             // 2048 shadow BN accumulators (memset below)
  float* aip     = fw + 7680;             // 65536
  float* ajp     = fw + 73216;            // 65536
  __hip_bfloat16* agg = (__hip_bfloat16*)(fw + 138752);  // 65536*64 bf16 = 8.39 MB
  __hip_bfloat16* xl  = (__hip_bfloat16*)(fw + 2235904); // 65536*64 bf16 = 8.39 MB
  float* part    = (float*)xl;            // 128*16384 f32 = 8.39 MB, aliases dead xl
  float* out     = (float*)d_out;

  hipMemsetAsync((void*)bnsum, 0, 2048u*sizeof(float), stream);

  k_gx       <<<1280,  256, 0, stream>>>(data, emb, lin_w, att_i, att_j, att_em_i, att_em_j,
                                         topk, emi, emj, xl, aip, ajp);
  k_attn_agg <<<1024,  256, 0, stream>>>(topk, xl, aip, ajp, emi, emj, gnn_bias, agg, bnsum);
  k_encstat  <<<dim3(128,4), 256, 0, stream>>>(agg, enc_w, emb, g1, be1, bnsum, part);
  k_redarr   <<<256,   256, 0, stream>>>(part, enc_b, arr_w, arr_b, out);
  k_score    <<<2048,  256, 0, stream>>>(agg, emb, g1, be1, g2, be2, bnsum, out_w, out_b, out);
}

// Round 13
// 174.369 us; speedup vs baseline: 1.5257x; 1.5257x over previous
//
#include <hip/hip_runtime.h>
#include <hip/hip_bf16.h>

#define TK 20
#define BN 65536

typedef const float* fpc;
typedef __attribute__((ext_vector_type(8))) short short8;
typedef __attribute__((ext_vector_type(4))) float floatx4;

// f32 -> bf16 bits, round-to-nearest-even
__device__ __forceinline__ short f2b(float f){
  unsigned u = __float_as_uint(f);
  return (short)((u + 0x7fffu + ((u >> 16) & 1u)) >> 16);
}
__device__ __forceinline__ float b2fu(unsigned short u){
  return __uint_as_float(((unsigned)u) << 16);
}

// ---------------- K1: fused graph (blocks 0..255, block 0 zeroes bnsum) + xl MFMA (256..1279) ----------------
__global__ void __launch_bounds__(256) k_gx(fpc data, fpc emb, fpc lin_w, fpc att_i, fpc att_j,
        fpc att_em_i, fpc att_em_j,
        int* __restrict__ topk, float* __restrict__ emi, float* __restrict__ emj,
        __hip_bfloat16* __restrict__ xl, float* __restrict__ aip, float* __restrict__ ajp,
        float* __restrict__ bnsum){
  __shared__ float s_cos[256];
  __shared__ float s_wi[64];
  const int t = threadIdx.x, w = t >> 6, lane = t & 63;

  if (blockIdx.x < 256){
    if (blockIdx.x == 0){
      #pragma unroll
      for (int i = 0; i < 8; ++i) bnsum[t + i*256] = 0.f;   // zero shadow BN accumulators
    }
    // ----- graph part: top-20 cosine + emi/emj -----
    const int i = blockIdx.x;
    if (t < 64) s_wi[t] = emb[i*64 + t];
    __syncthreads();
    float dot = 0.f, nj = 0.f, ni = 0.f;
    for (int f = 0; f < 64; ++f){
      float wj = emb[t*64 + f], wi = s_wi[f];
      dot = fmaf(wi, wj, dot); nj = fmaf(wj, wj, nj); ni = fmaf(wi, wi, ni);
    }
    s_cos[t] = dot / (sqrtf(ni) * sqrtf(nj));
    __syncthreads();
    if (t < 64){
      float v0 = s_cos[t], v1 = s_cos[t+64], v2 = s_cos[t+128], v3 = s_cos[t+192];
      int taken = 0;
      for (int r = 0; r < TK; ++r){
        float bv = (taken & 1) ? -3.f : v0; int bi = t;
        float c;
        c = (taken & 2) ? -3.f : v1; if (c > bv){ bv = c; bi = t+64;  }
        c = (taken & 4) ? -3.f : v2; if (c > bv){ bv = c; bi = t+128; }
        c = (taken & 8) ? -3.f : v3; if (c > bv){ bv = c; bi = t+192; }
        for (int m = 1; m < 64; m <<= 1){
          float ov = __shfl_xor(bv, m, 64);
          int   oi = __shfl_xor(bi, m, 64);
          if (ov > bv || (ov == bv && oi < bi)){ bv = ov; bi = oi; }
        }
        if (t == 0) topk[i*TK + r] = bi;
        if ((bi & 63) == t) taken |= 1 << (bi >> 6);
      }
    } else if (t < 128){
      int d = t - 64;
      float wv = s_wi[d];
      float p1 = wv * att_em_i[d];
      float p2 = wv * att_em_j[d];
      for (int m = 1; m < 64; m <<= 1){
        p1 += __shfl_xor(p1, m, 64);
        p2 += __shfl_xor(p2, m, 64);
      }
      if (d == 0){ emi[i] = p1; emj[i] = p2; }
    }
    return;
  }

  // ----- xl part: data @ lin_w via MFMA 16x16x32 bf16 -----
  const int m = lane & 15, quad = lane >> 4;
  short8 B[4][2];
  #pragma unroll
  for (int ct = 0; ct < 4; ++ct)
    #pragma unroll
    for (int kc = 0; kc < 2; ++kc)
      #pragma unroll
      for (int j = 0; j < 8; ++j)
        B[ct][kc][j] = f2b(lin_w[(kc*32 + quad*8 + j)*64 + ct*16 + m]);

  const int rw = (blockIdx.x - 256)*64 + w*16;  // 1024 blocks x 64 rows
  short8 A0, A1;
  {
    const float4* ap0 = (const float4*)(data + (size_t)(rw + m)*64 + quad*8);
    float4 q0 = ap0[0], q1 = ap0[1];
    A0[0]=f2b(q0.x); A0[1]=f2b(q0.y); A0[2]=f2b(q0.z); A0[3]=f2b(q0.w);
    A0[4]=f2b(q1.x); A0[5]=f2b(q1.y); A0[6]=f2b(q1.z); A0[7]=f2b(q1.w);
    const float4* ap1 = (const float4*)(data + (size_t)(rw + m)*64 + 32 + quad*8);
    float4 q2 = ap1[0], q3 = ap1[1];
    A1[0]=f2b(q2.x); A1[1]=f2b(q2.y); A1[2]=f2b(q2.z); A1[3]=f2b(q2.w);
    A1[4]=f2b(q3.x); A1[5]=f2b(q3.y); A1[6]=f2b(q3.z); A1[7]=f2b(q3.w);
  }
  floatx4 acc[4];
  #pragma unroll
  for (int ct = 0; ct < 4; ++ct){
    floatx4 z = {0.f, 0.f, 0.f, 0.f};
    acc[ct] = __builtin_amdgcn_mfma_f32_16x16x32_bf16(A0, B[ct][0], z, 0, 0, 0);
    acc[ct] = __builtin_amdgcn_mfma_f32_16x16x32_bf16(A1, B[ct][1], acc[ct], 0, 0, 0);
  }
  float p1[4] = {0.f,0.f,0.f,0.f}, p2[4] = {0.f,0.f,0.f,0.f};
  #pragma unroll
  for (int ct = 0; ct < 4; ++ct){
    const float wi = att_i[ct*16 + m], wj = att_j[ct*16 + m];
    #pragma unroll
    for (int reg = 0; reg < 4; ++reg){
      float v = acc[ct][reg];
      const int row = rw + quad*4 + reg;
      xl[(size_t)row*64 + ct*16 + m] = __float2bfloat16(v);
      p1[reg] = fmaf(v, wi, p1[reg]);
      p2[reg] = fmaf(v, wj, p2[reg]);
    }
  }
  #pragma unroll
  for (int reg = 0; reg < 4; ++reg){
    #pragma unroll
    for (int s = 1; s < 16; s <<= 1){
      p1[reg] += __shfl_xor(p1[reg], s, 16);
      p2[reg] += __shfl_xor(p2[reg], s, 16);
    }
    if (m == 0){
      const int r = rw + quad*4 + reg;
      aip[r] = p1[reg];                      // emi/emj added in k_attn_agg
      ajp[r] = p2[reg];
    }
  }
}

// ---------------- K2: edge softmax + gather aggregation (bf16 agg out) + bn1 shadow stats ----------------
__global__ void __launch_bounds__(256) k_attn_agg(const int* __restrict__ topk,
                         const __hip_bfloat16* __restrict__ xl,
                         fpc aip, fpc ajp, fpc emi_g, fpc emj_g, fpc gnn_bias,
                         __hip_bfloat16* __restrict__ agg, float* __restrict__ bnsum){
  __shared__ float s_alpha[4][32];
  __shared__ int   s_src[4][32];
  __shared__ float s_ps[4][64], s_pq[4][64];
  const int t = threadIdx.x, w = t >> 6, lane = t & 63;
  const float bias = gnn_bias[lane];
  const int vbase = blockIdx.x*64 + w*16;    // 1024 blocks x 64 nodes; 16/wave
  float sum = 0.f, sq = 0.f;
  for (int j = 0; j < 16; ++j){
    const int v = vbase + j, i = v & 255, b = v >> 8;
    float lg = -1e30f; int sl = 0;
    if (lane < 21){
      sl = (lane < 20) ? topk[i*TK + lane] : i;
      if (lane == 20 || sl != i){            // remove_self_loops, keep appended loop
        float l = aip[v] + emi_g[i] + ajp[b*256 + sl] + emj_g[sl];
        lg = (l >= 0.f) ? l : 0.2f*l;        // leaky_relu(0.2)
      }
    }
    float m = lg;
    for (int s = 1; s < 32; s <<= 1) m = fmaxf(m, __shfl_xor(m, s, 32));
    float e = (lg > -1e29f) ? __expf(lg - m) : 0.f;
    float den = e;
    for (int s = 1; s < 32; s <<= 1) den += __shfl_xor(den, s, 32);
    if (lane < 21){ s_alpha[w][lane] = e / den; s_src[w][lane] = b*256 + sl; }
    float acc = bias;
    #pragma unroll
    for (int k = 0; k < 21; ++k)
      acc = fmaf(s_alpha[w][k], __bfloat162float(xl[(size_t)s_src[w][k]*64 + lane]), acc);
    agg[(size_t)v*64 + lane] = __float2bfloat16(acc);
    sum += acc; sq = fmaf(acc, acc, sq);
  }
  s_ps[w][lane] = sum; s_pq[w][lane] = sq;
  __syncthreads();
  if (t < 64){
    const int cp = (blockIdx.x & 7)*64;
    atomicAdd(&bnsum[cp + t],       s_ps[0][t] + s_ps[1][t] + s_ps[2][t] + s_ps[3][t]);
    atomicAdd(&bnsum[512 + cp + t], s_pq[0][t] + s_pq[1][t] + s_pq[2][t] + s_pq[3][t]);
  }
}

// ---------------- K3: block-range split -- enc MFMA (blocks 0..255) | bn2 stats (256..2303) ----------------
__global__ void __launch_bounds__(256) k_encst(const __hip_bfloat16* __restrict__ agg, fpc enc_w,
                         fpc emb, fpc g1, fpc be1,
                         float* __restrict__ bnsum, float* __restrict__ part){
  const int t = threadIdx.x;

  if (blockIdx.x < 256){
    // ===== enc path (round-11 no-spill shape): kt in [0,128), bt in [0,2) =====
    const int w = t >> 6, lane = t & 63;
    const int m = lane & 15, quad = lane >> 4;
    const int kt = blockIdx.x & 127, bt = blockIdx.x >> 7, kbase = kt*128;
    float scA[8], shA[8], scB[8], shB[8];
    #pragma unroll
    for (int j = 0; j < 8; ++j){
      #pragma unroll
      for (int par = 0; par < 2; ++par){
        const int d = par*32 + quad*8 + j;
        float S = 0.f, Q = 0.f;
        #pragma unroll
        for (int cp = 0; cp < 8; ++cp){ S += bnsum[cp*64 + d]; Q += bnsum[512 + cp*64 + d]; }
        float mean = S * (1.f/BN);
        float var  = Q * (1.f/BN) - mean*mean;
        float sc = g1[d] * rsqrtf(var + 1e-5f);
        float sh = be1[d] - mean*sc;
        if (par == 0){ scA[j] = sc; shA[j] = sh; } else { scB[j] = sc; shB[j] = sh; }
      }
    }
    floatx4 acc[2][4];
    #pragma unroll
    for (int i = 0; i < 2; ++i)
      #pragma unroll
      for (int ct = 0; ct < 4; ++ct)
        acc[i][ct] = (floatx4){0.f, 0.f, 0.f, 0.f};

    #pragma unroll
    for (int kc = 0; kc < 4; ++kc){
      const int kof = kbase + kc*32 + quad*8;
      const bool odd = (kc & 1);
      short8 Bf[4];
      #pragma unroll
      for (int ct = 0; ct < 4; ++ct)
        #pragma unroll
        for (int j = 0; j < 8; ++j)
          Bf[ct][j] = f2b(enc_w[(size_t)(kof + j)*64 + ct*16 + m]);
      #pragma unroll
      for (int i = 0; i < 2; ++i){
        const int row = bt*128 + (w*2 + i)*16 + m;
        uint4 uu = *(const uint4*)((const unsigned short*)agg + (size_t)row*16384 + kof);
        unsigned short h[8] = {
          (unsigned short)(uu.x & 0xffff), (unsigned short)(uu.x >> 16),
          (unsigned short)(uu.y & 0xffff), (unsigned short)(uu.y >> 16),
          (unsigned short)(uu.z & 0xffff), (unsigned short)(uu.z >> 16),
          (unsigned short)(uu.w & 0xffff), (unsigned short)(uu.w >> 16) };
        short8 Af;
        if (!odd){
          #pragma unroll
          for (int j = 0; j < 8; ++j) Af[j] = f2b(fmaxf(fmaf(b2fu(h[j]), scA[j], shA[j]), 0.f));
        } else {
          #pragma unroll
          for (int j = 0; j < 8; ++j) Af[j] = f2b(fmaxf(fmaf(b2fu(h[j]), scB[j], shB[j]), 0.f));
        }
        #pragma unroll
        for (int ct = 0; ct < 4; ++ct)
          acc[i][ct] = __builtin_amdgcn_mfma_f32_16x16x32_bf16(Af, Bf[ct], acc[i][ct], 0, 0, 0);
      }
    }
    #pragma unroll
    for (int i = 0; i < 2; ++i)
      #pragma unroll
      for (int ct = 0; ct < 4; ++ct)
        #pragma unroll
        for (int reg = 0; reg < 4; ++reg){
          const int row = bt*128 + (w*2 + i)*16 + quad*4 + reg;
          part[(size_t)kt*16384 + row*64 + ct*16 + m] = acc[i][ct][reg];
        }
    return;
  }

  // ===== stats path: bn2 stats over bf16 agg (2048 blocks x 32 rows) =====
  const int sb = blockIdx.x - 256;
  const int qc = t & 15, rs = t >> 4;
  float4 sc, sh;
  {
    float s[4], q[4];
    #pragma unroll
    for (int k = 0; k < 4; ++k){
      const int d = qc*4 + k;
      float S = 0.f, Q = 0.f;
      #pragma unroll
      for (int cp = 0; cp < 8; ++cp){ S += bnsum[cp*64 + d]; Q += bnsum[512 + cp*64 + d]; }
      float mean = S * (1.f/BN);
      float var  = Q * (1.f/BN) - mean*mean;
      s[k] = g1[d] * rsqrtf(var + 1e-5f);
      q[k] = be1[d] - mean*s[k];
    }
    sc = make_float4(s[0], s[1], s[2], s[3]);
    sh = make_float4(q[0], q[1], q[2], q[3]);
  }
  const float4* emb4 = (const float4*)emb;
  float4 ys = make_float4(0,0,0,0), yq = make_float4(0,0,0,0);
  const int rbase = sb*32;
  #pragma unroll
  for (int jj = 0; jj < 2; ++jj){
    const int r = rbase + jj*16 + rs;
    ushort4 u = *(const ushort4*)((const unsigned short*)agg + (size_t)r*64 + qc*4);
    float4 e = emb4[(r & 255)*16 + qc];
    float4 y;
    y.x = fmaxf(fmaf(b2fu(u.x), sc.x, sh.x), 0.f) * e.x;
    y.y = fmaxf(fmaf(b2fu(u.y), sc.y, sh.y), 0.f) * e.y;
    y.z = fmaxf(fmaf(b2fu(u.z), sc.z, sh.z), 0.f) * e.z;
    y.w = fmaxf(fmaf(b2fu(u.w), sc.w, sh.w), 0.f) * e.w;
    ys.x += y.x; ys.y += y.y; ys.z += y.z; ys.w += y.w;
    yq.x = fmaf(y.x, y.x, yq.x); yq.y = fmaf(y.y, y.y, yq.y);
    yq.z = fmaf(y.z, y.z, yq.z); yq.w = fmaf(y.w, y.w, yq.w);
  }
  __shared__ float4 s_s[16][16], s_q[16][16];
  s_s[rs][qc] = ys; s_q[rs][qc] = yq;
  __syncthreads();
  if (t < 64){
    const int qq = t >> 2, comp = t & 3;
    float S = 0.f, Q = 0.f;
    #pragma unroll
    for (int rr = 0; rr < 16; ++rr){
      S += ((const float*)&s_s[rr][qq])[comp];
      Q += ((const float*)&s_q[rr][qq])[comp];
    }
    const int cp = (sb & 7)*64;
    atomicAdd(&bnsum[1024 + cp + t], S);
    atomicAdd(&bnsum[1536 + cp + t], Q);
  }
}

// ---------------- K4: block-range split -- redarr (blocks 0..255) | score (256..2303) ----------------
__global__ void __launch_bounds__(256) k_fin(const float* __restrict__ part,
                      const __hip_bfloat16* __restrict__ agg, fpc emb,
                      fpc g1, fpc be1, fpc g2, fpc be2,
                      const float* __restrict__ bnsum,
                      fpc enc_b, fpc arr_w, fpc arr_b, fpc out_w, fpc out_b,
                      float* __restrict__ out){
  const int t = threadIdx.x;

  if (blockIdx.x < 256){
    // ===== redarr path: reduce split-K partials + arrangement head =====
    __shared__ float s_enc[4][64];
    const int b = blockIdx.x, w = t >> 6, lane = t & 63;
    float s = 0.f;
    #pragma unroll 8
    for (int k = 0; k < 32; ++k)
      s += part[(size_t)(w*32 + k)*16384 + b*64 + lane];
    s_enc[w][lane] = s;
    __syncthreads();
    if (t < 64){
      float e = s_enc[0][t] + s_enc[1][t] + s_enc[2][t] + s_enc[3][t] + enc_b[t];
      float o[7];
      #pragma unroll
      for (int j = 0; j < 7; ++j) o[j] = e * arr_w[t*7 + j];
      #pragma unroll
      for (int j = 0; j < 7; ++j)
        #pragma unroll
        for (int m = 1; m < 64; m <<= 1) o[j] += __shfl_xor(o[j], m, 64);
      if (t == 0){
        #pragma unroll
        for (int j = 0; j < 7; ++j) out[65536 + b*7 + j] = o[j] + arr_b[j];
      }
    }
    return;
  }

  // ===== score path =====
  const int w = t >> 6, lane = t & 63;
  const int qc = lane & 15, rq = lane >> 4;
  float sc1[4], sh1[4], sc2[4], sh2[4], ow[4];
  #pragma unroll
  for (int k = 0; k < 4; ++k){
    const int d = qc*4 + k;
    float S1 = 0.f, Q1 = 0.f, S2 = 0.f, Q2 = 0.f;
    #pragma unroll
    for (int cp = 0; cp < 8; ++cp){
      S1 += bnsum[cp*64 + d];        Q1 += bnsum[512 + cp*64 + d];
      S2 += bnsum[1024 + cp*64 + d]; Q2 += bnsum[1536 + cp*64 + d];
    }
    float m1 = S1 * (1.f/BN), v1 = Q1 * (1.f/BN) - m1*m1;
    sc1[k] = g1[d] * rsqrtf(v1 + 1e-5f);
    sh1[k] = be1[d] - m1*sc1[k];
    float m2 = S2 * (1.f/BN), v2 = Q2 * (1.f/BN) - m2*m2;
    sc2[k] = g2[d] * rsqrtf(v2 + 1e-5f);
    sh2[k] = be2[d] - m2*sc2[k];
    ow[k]  = out_w[d];
  }
  const float ob = out_b[0];
  const float4* emb4 = (const float4*)emb;
  const int base = (blockIdx.x - 256)*32 + w*8;
  #pragma unroll
  for (int it = 0; it < 2; ++it){
    const int r = base + it*4 + rq;
    ushort4 u = *(const ushort4*)((const unsigned short*)agg + (size_t)r*64 + qc*4);
    float4 e4 = emb4[(r & 255)*16 + qc];
    float p = 0.f, g, y, yh;
    g = fmaxf(fmaf(b2fu(u.x), sc1[0], sh1[0]), 0.f); y = g*e4.x;
    yh = fmaxf(fmaf(y, sc2[0], sh2[0]), 0.f); p = fmaf(yh, ow[0], p);
    g = fmaxf(fmaf(b2fu(u.y), sc1[1], sh1[1]), 0.f); y = g*e4.y;
    yh = fmaxf(fmaf(y, sc2[1], sh2[1]), 0.f); p = fmaf(yh, ow[1], p);
    g = fmaxf(fmaf(b2fu(u.z), sc1[2], sh1[2]), 0.f); y = g*e4.z;
    yh = fmaxf(fmaf(y, sc2[2], sh2[2]), 0.f); p = fmaf(yh, ow[2], p);
    g = fmaxf(fmaf(b2fu(u.w), sc1[3], sh1[3]), 0.f); y = g*e4.w;
    yh = fmaxf(fmaf(y, sc2[3], sh2[3]), 0.f); p = fmaf(yh, ow[3], p);
    #pragma unroll
    for (int mm = 1; mm < 16; mm <<= 1) p += __shfl_xor(p, mm, 16);
    if (qc == 0) out[r] = p + ob;
  }
}

extern "C" void kernel_launch(void* const* d_in, const int* in_sizes, int n_in,
                              void* d_out, int out_size, void* d_ws, size_t ws_size,
                              hipStream_t stream) {
  fpc data     = (fpc)d_in[0];
  fpc emb      = (fpc)d_in[1];
  fpc lin_w    = (fpc)d_in[2];
  fpc att_i    = (fpc)d_in[3];
  fpc att_j    = (fpc)d_in[4];
  fpc att_em_i = (fpc)d_in[5];
  fpc att_em_j = (fpc)d_in[6];
  fpc gnn_bias = (fpc)d_in[7];
  fpc g1       = (fpc)d_in[8];
  fpc be1      = (fpc)d_in[9];
  fpc g2       = (fpc)d_in[10];
  fpc be2      = (fpc)d_in[11];
  fpc enc_w    = (fpc)d_in[12];
  fpc enc_b    = (fpc)d_in[13];
  fpc arr_w    = (fpc)d_in[14];
  fpc arr_b    = (fpc)d_in[15];
  fpc out_w    = (fpc)d_in[16];
  fpc out_b    = (fpc)d_in[17];

  float* fw = (float*)d_ws;
  int*   topk    = (int*)d_ws;            // [0, 5120)
  float* emi     = fw + 5120;             // 256
  float* emj     = fw + 5376;             // 256
  float* bnsum   = fw + 5632;             // 2048 shadow BN accumulators (zeroed by k_gx block 0)
  float* aip     = fw + 7680;             // 65536
  float* ajp     = fw + 73216;            // 65536
  __hip_bfloat16* agg = (__hip_bfloat16*)(fw + 138752);  // 65536*64 bf16 = 8.39 MB
  __hip_bfloat16* xl  = (__hip_bfloat16*)(fw + 2235904); // 65536*64 bf16 = 8.39 MB
  float* part    = (float*)xl;            // 128*16384 f32 = 8.39 MB, aliases dead xl
  float* out     = (float*)d_out;

  k_gx       <<<1280,  256, 0, stream>>>(data, emb, lin_w, att_i, att_j, att_em_i, att_em_j,
                                         topk, emi, emj, xl, aip, ajp, bnsum);
  k_attn_agg <<<1024,  256, 0, stream>>>(topk, xl, aip, ajp, emi, emj, gnn_bias, agg, bnsum);
  k_encst    <<<2304,  256, 0, stream>>>(agg, enc_w, emb, g1, be1, bnsum, part);
  k_fin      <<<2304,  256, 0, stream>>>(part, agg, emb, g1, be1, g2, be2, bnsum,
                                         enc_b, arr_w, arr_b, out_w, out_b, out);
}